// Round 2
// baseline (129.395 us; speedup 1.0000x reference)
//
#include <hip/hip_runtime.h>
#include <hip/hip_bf16.h>

typedef __attribute__((ext_vector_type(8))) short short8;
typedef __attribute__((ext_vector_type(4))) float float4v;

#define N_ROWS 4096
#define K_DIM  192
#define TILE   128
#define NT     32          // 4096/128 tiles per dim
#define NSYM   528         // 32*33/2 upper-triangular blocks
#define NBLK   2080        // 2*528 + 1024
#define C1     (-0.72134752044448179f)   // -0.5*log2(e)
#define LOG2E  (1.4426950408889634f)

typedef const __attribute__((address_space(1))) unsigned int* gp_t;
typedef __attribute__((address_space(3))) unsigned int* lp_t;

__device__ __forceinline__ void gload16(const void* g, void* l) {
    // async global->LDS, 16B per lane, dest = wave-uniform base + lane*16
    __builtin_amdgcn_global_load_lds((gp_t)g, (lp_t)l, 16, 0, 0);
}

__device__ __forceinline__ int div12(int x) {   // exact for 0 <= x < 2048
    return (x * 683) >> 13;
}

// ---- kernel 1: fp32 -> bf16 convert + per-row sum of squares (of bf16 values) ----
__global__ void prep_kernel(const float* __restrict__ x, const float* __restrict__ y,
                            __hip_bfloat16* __restrict__ xb, __hip_bfloat16* __restrict__ yb,
                            float* __restrict__ sqx, float* __restrict__ sqy,
                            unsigned* __restrict__ ctrl /* 3 float sums + 1 counter */)
{
    if (blockIdx.x == 0 && threadIdx.x < 4) ctrl[threadIdx.x] = 0u;  // zero sums + counter
    int w    = (blockIdx.x * blockDim.x + threadIdx.x) >> 6;  // one row per wave
    int lane = threadIdx.x & 63;
    if (w >= 2 * N_ROWS) return;
    const float*      src = (w < N_ROWS) ? (x + (size_t)w * K_DIM) : (y + (size_t)(w - N_ROWS) * K_DIM);
    __hip_bfloat16*   dst = (w < N_ROWS) ? (xb + (size_t)w * K_DIM) : (yb + (size_t)(w - N_ROWS) * K_DIM);
    float s = 0.f;
    #pragma unroll
    for (int i = 0; i < 3; ++i) {                // 192 = 3 * 64
        float f = src[lane + 64 * i];
        __hip_bfloat16 h = __float2bfloat16(f);
        dst[lane + 64 * i] = h;
        float fb = __bfloat162float(h);
        s += fb * fb;
    }
    #pragma unroll
    for (int off = 32; off; off >>= 1) s += __shfl_down(s, off, 64);
    if (lane == 0) {
        if (w < N_ROWS) sqx[w] = s; else sqy[w - N_ROWS] = s;
    }
}

// ---- kernel 2: fused Gram + exp + reduce + (last block) final loss ----
// block = 256 threads (4 waves, 2x2 quadrants of a 128x128 tile)
// LDS layout per stage: row-major 128 x 96 bf16, NO pad; column chunks of 8
// elems rotated per row: LDS(row, j) holds global chunk (j + row) mod 12.
__global__ __launch_bounds__(256, 3)
void gram_kernel(const __hip_bfloat16* __restrict__ xb, const __hip_bfloat16* __restrict__ yb,
                 const float* __restrict__ sqx, const float* __restrict__ sqy,
                 float* __restrict__ sums, unsigned* __restrict__ counter,
                 const float* __restrict__ avg_step, float* __restrict__ out)
{
    __shared__ short lA[TILE * 96];
    __shared__ short lB[TILE * 96];
    __shared__ float wred[4];

    const short* xbs = (const short*)xb;
    const short* ybs = (const short*)yb;

    int id = blockIdx.x;
    const short *A, *B; const float *sa, *sb;
    int bi, bj, cls;
    float weight = 1.0f;
    if (id < 2 * NSYM) {
        int t;
        if (id < NSYM) { t = id;        A = xbs; B = xbs; sa = sqx; sb = sqx; cls = 0; }
        else           { t = id - NSYM; A = ybs; B = ybs; sa = sqy; sb = sqy; cls = 1; }
        bi = 0;
        while (t >= NT - bi) { t -= NT - bi; ++bi; }   // unrank upper triangle
        bj = bi + t;
        if (bi != bj) weight = 2.0f;                   // symmetry: off-diagonal counts twice
    } else {
        int t = id - 2 * NSYM;
        bi = t >> 5; bj = t & 31;
        A = xbs; B = ybs; sa = sqx; sb = sqy; cls = 2;
    }
    const int abase = bi * TILE, bbase = bj * TILE;

    const int tid  = threadIdx.x;
    const int lane = tid & 63, w = tid >> 6;
    const int wm   = w >> 1,  wn = w & 1;
    const int m15  = lane & 15, quad = lane >> 4;

    // ---- per-lane swizzled global offsets for staging (shorts) ----
    int rowoff[6];
    #pragma unroll
    for (int it = 0; it < 6; ++it) {
        int ci  = it * 256 + tid;          // 16B-chunk index, 0..1535
        int row = div12(ci);
        int j   = ci - row * 12;
        int rot = row - div12(row) * 12;   // row mod 12
        int t   = j + rot; if (t >= 12) t -= 12;
        rowoff[it] = row * K_DIM + t * 8;  // element offset within 128-row panel
    }
    const short* Apan = A + (size_t)abase * K_DIM;
    const short* Bpan = B + (size_t)bbase * K_DIM;
    char* lAb = (char*)lA;
    char* lBb = (char*)lB;

    // ---- issue stage-0 loads ASAP ----
    #pragma unroll
    for (int it = 0; it < 6; ++it) {
        int ldso = (it * 256 + w * 64) * 16;   // wave-uniform LDS byte base
        gload16(Apan + rowoff[it], lAb + ldso);
        gload16(Bpan + rowoff[it], lBb + ldso);
    }

    // ---- precompute LDS read addresses (identical for both stages) ----
    int adA[3][4], adB[3][4];
    #pragma unroll
    for (int tm = 0; tm < 4; ++tm) {
        int rA = wm * 64 + tm * 16 + m15;
        int mA = rA - div12(rA) * 12; int nA = (mA == 0) ? 0 : (12 - mA);
        int rB = wn * 64 + tm * 16 + m15;
        int mB = rB - div12(rB) * 12; int nB = (mB == 0) ? 0 : (12 - mB);
        #pragma unroll
        for (int ks = 0; ks < 3; ++ks) {
            int c  = ks * 4 + quad;
            int ja = c + nA; if (ja >= 12) ja -= 12;
            int jb = c + nB; if (jb >= 12) jb -= 12;
            adA[ks][tm] = rA * 192 + ja * 16;   // LDS byte addr (row stride 192B)
            adB[ks][tm] = rB * 192 + jb * 16;
        }
    }

    // ---- sq terms (scaled by C1) ----
    float4v ua[4]; float vb4[4];
    #pragma unroll
    for (int tm = 0; tm < 4; ++tm)
        ua[tm] = (*(const float4v*)&sa[abase + wm * 64 + tm * 16 + quad * 4]) * C1;
    #pragma unroll
    for (int tn = 0; tn < 4; ++tn)
        vb4[tn] = C1 * sb[bbase + wn * 64 + tn * 16 + m15];

    float4v acc[4][4];
    #pragma unroll
    for (int i = 0; i < 4; ++i)
        #pragma unroll
        for (int j = 0; j < 4; ++j) acc[i][j] = (float4v){0.f, 0.f, 0.f, 0.f};

    // ---- two K-stages of 96 ----
    #pragma unroll
    for (int s = 0; s < 2; ++s) {
        __syncthreads();   // drains vmcnt for the stage's global_load_lds
        #pragma unroll
        for (int ks = 0; ks < 3; ++ks) {
            short8 af[4], bfr[4];
            #pragma unroll
            for (int tm = 0; tm < 4; ++tm) af[tm]  = *(const short8*)(lAb + adA[ks][tm]);
            #pragma unroll
            for (int tn = 0; tn < 4; ++tn) bfr[tn] = *(const short8*)(lBb + adB[ks][tn]);
            #pragma unroll
            for (int tm = 0; tm < 4; ++tm)
                #pragma unroll
                for (int tn = 0; tn < 4; ++tn)
                    acc[tm][tn] = __builtin_amdgcn_mfma_f32_16x16x32_bf16(af[tm], bfr[tn], acc[tm][tn], 0, 0, 0);
        }
        if (s == 0) {
            __syncthreads();   // all stage-0 LDS reads done before overwrite
            #pragma unroll
            for (int it = 0; it < 6; ++it) {
                int ldso = (it * 256 + w * 64) * 16;
                gload16(Apan + 96 + rowoff[it], lAb + ldso);
                gload16(Bpan + 96 + rowoff[it], lBb + ldso);
            }
        }
    }

    // ---- epilogue: sum exp2(min(C1*sqa + C1*sqb + log2e*g, 0)), skipping underflow tiles ----
    float lsum = 0.f;
    #pragma unroll
    for (int tm = 0; tm < 4; ++tm)
        #pragma unroll
        for (int tn = 0; tn < 4; ++tn) {
            float vv = vb4[tn];
            float s0 = fminf(ua[tm][0] + vv + LOG2E * acc[tm][tn][0], 0.f);
            float s1 = fminf(ua[tm][1] + vv + LOG2E * acc[tm][tn][1], 0.f);
            float s2 = fminf(ua[tm][2] + vv + LOG2E * acc[tm][tn][2], 0.f);
            float s3 = fminf(ua[tm][3] + vv + LOG2E * acc[tm][tn][3], 0.f);
            float mx = fmaxf(fmaxf(s0, s1), fmaxf(s2, s3));
            if (__ballot(mx > -40.f)) {   // whole 16x16 tile underflows -> skip (execz)
                lsum += __builtin_amdgcn_exp2f(s0) + __builtin_amdgcn_exp2f(s1)
                      + __builtin_amdgcn_exp2f(s2) + __builtin_amdgcn_exp2f(s3);
            }
        }

    #pragma unroll
    for (int off = 32; off; off >>= 1) lsum += __shfl_down(lsum, off, 64);
    if (lane == 0) wred[w] = lsum;
    __syncthreads();
    if (tid == 0) {
        float p = weight * (wred[0] + wred[1] + wred[2] + wred[3]);
        atomicAdd(&sums[cls], p);
        __threadfence();
        unsigned done = atomicAdd(counter, 1u);
        if (done == NBLK - 1) {            // last block finalizes
            __threadfence();
            float sxx = atomicAdd(&sums[0], 0.0f);
            float syy = atomicAdd(&sums[1], 0.0f);
            float sxy = atomicAdd(&sums[2], 0.0f);
            const float inv = 1.0f / 16777216.0f;   // 1/4096^2
            float mmd   = (sxx + syy - 2.0f * sxy) * inv;
            float stepv = fmaxf(1.0f, avg_step[0]);
            out[0] = mmd + (stepv - 1.0f) * 0.002f;
            out[1] = mmd;
        }
    }
}

extern "C" void kernel_launch(void* const* d_in, const int* in_sizes, int n_in,
                              void* d_out, int out_size, void* d_ws, size_t ws_size,
                              hipStream_t stream)
{
    const float* x        = (const float*)d_in[0];
    const float* y        = (const float*)d_in[1];
    const float* avg_step = (const float*)d_in[2];

    char* ws = (char*)d_ws;
    // ws layout: xb | yb | sqx | sqy | sums(3 f32) + counter(1 u32)
    __hip_bfloat16* xb      = (__hip_bfloat16*)(ws);
    __hip_bfloat16* yb      = (__hip_bfloat16*)(ws + 1572864);
    float*          sqx     = (float*)(ws + 3145728);
    float*          sqy     = (float*)(ws + 3162112);
    float*          sums    = (float*)(ws + 3178496);
    unsigned*       counter = (unsigned*)(ws + 3178508);

    prep_kernel<<<2048, 256, 0, stream>>>(x, y, xb, yb, sqx, sqy, (unsigned*)sums);
    gram_kernel<<<NBLK, 256, 0, stream>>>(xb, yb, sqx, sqy, sums, counter,
                                          avg_step, (float*)d_out);
}